// Round 1
// baseline (104.177 us; speedup 1.0000x reference)
//
#include <hip/hip_runtime.h>

// Problem: spec (32, 4000, 161, 2) f32.
//   g0[b,t]   = sqrt((2*sum(pow[1:160]) + pow[0] + pow[160]) / 320)
//   gain[b,t] = EMA over t: c = 0.9c + 0.1*g0   (gain[b,0] = g0[b,0])
//   new_spec  = spec / (gain + 0.001)
// Outputs flat-concat: new_spec (41,216,000 f32) then gain (128,000 f32).

#define B_SZ 32
#define T_SZ 4000
#define BINS 161
#define FRAME_F 322          // floats per frame (161 bins * 2)
#define FRAMES (B_SZ * T_SZ) // 128000
#define N_SPEC ((size_t)FRAMES * FRAME_F)
#define EMA_W 384            // 0.9^384 ~ 4e-18: below f32 resolution

// ---- Kernel 1: per-frame gain g0. One 64-lane wave per frame. ----
__global__ __launch_bounds__(256) void k_frame_gain(
    const float* __restrict__ spec, float* __restrict__ g0, int frames) {
  int gtid = blockIdx.x * blockDim.x + threadIdx.x;
  int wid  = gtid >> 6;          // frame id
  int lane = threadIdx.x & 63;
  if (wid >= frames) return;

  const float* fp = spec + (size_t)wid * FRAME_F;
  float acc = 0.f;
#pragma unroll
  for (int i = 0; i < 3; ++i) {
    int bin = lane + i * 64;
    if (bin < BINS) {
      float2 v = *(const float2*)(fp + bin * 2);
      float w = (bin == 0 || bin == BINS - 1) ? 1.f : 2.f;
      acc += w * (v.x * v.x + v.y * v.y);
    }
  }
#pragma unroll
  for (int off = 32; off > 0; off >>= 1) acc += __shfl_xor(acc, off, 64);
  if (lane == 0) g0[wid] = sqrtf(acc * (1.0f / 320.0f));
}

// ---- Kernel 2: EMA via truncated window (exact for t < EMA_W). ----
// grid: (T/256, B); block 256. LDS stages g0[b, lo .. t0+255].
__global__ __launch_bounds__(256) void k_ema(
    const float* __restrict__ g0, float* __restrict__ gain_out) {
  __shared__ float xs[EMA_W + 256];
  int b  = blockIdx.y;
  int t0 = blockIdx.x * 256;
  int lo = t0 - (EMA_W - 1); if (lo < 0) lo = 0;
  int hi = t0 + 256; if (hi > T_SZ) hi = T_SZ;   // exclusive
  int n  = hi - lo;
  const float* gb = g0 + b * T_SZ;

  for (int i = threadIdx.x; i < n; i += 256) xs[i] = gb[lo + i];
  __syncthreads();

  int t = t0 + (int)threadIdx.x;
  if (t >= T_SZ) return;
  int s = t - (EMA_W - 1); if (s < 1) s = 1;
  float c = (s == 1) ? xs[0 - lo + 0] : 0.f;  // lo==0 whenever s==1
  for (int k = s; k <= t; ++k) c = c * 0.9f + xs[k - lo] * 0.1f;
  gain_out[b * T_SZ + t] = c;
}

// ---- Kernel 3: new_spec = spec / (gain + 0.001). One wave per frame. ----
__global__ __launch_bounds__(256) void k_apply(
    const float* __restrict__ spec, const float* __restrict__ gain,
    float* __restrict__ out, int frames) {
  int gtid = blockIdx.x * blockDim.x + threadIdx.x;
  int wid  = gtid >> 6;
  int lane = threadIdx.x & 63;
  if (wid >= frames) return;

  float inv = 1.0f / (gain[wid] + 0.001f);
  const float* fp = spec + (size_t)wid * FRAME_F;
  float*       op = out  + (size_t)wid * FRAME_F;
#pragma unroll
  for (int i = 0; i < 3; ++i) {
    int bin = lane + i * 64;
    if (bin < BINS) {
      float2 v = *(const float2*)(fp + bin * 2);
      v.x *= inv; v.y *= inv;
      *(float2*)(op + bin * 2) = v;
    }
  }
}

extern "C" void kernel_launch(void* const* d_in, const int* in_sizes, int n_in,
                              void* d_out, int out_size, void* d_ws, size_t ws_size,
                              hipStream_t stream) {
  const float* spec = (const float*)d_in[0];
  float* out  = (float*)d_out;
  float* gain = out + N_SPEC;        // gain lives in the d_out tail
  float* g0   = (float*)d_ws;        // 128000 f32 = 512 KB scratch

  int frames = FRAMES;

  // K1: 4 waves (frames) per 256-thread block
  int blocks1 = (frames + 3) / 4;
  k_frame_gain<<<blocks1, 256, 0, stream>>>(spec, g0, frames);

  // K2: grid (T/256, B)
  dim3 g2((T_SZ + 255) / 256, B_SZ);
  k_ema<<<g2, 256, 0, stream>>>(g0, gain);

  // K3: 4 frames per block
  k_apply<<<blocks1, 256, 0, stream>>>(spec, gain, out, frames);
}

// Round 2
// 100.162 us; speedup vs baseline: 1.0401x; 1.0401x over previous
//
#include <hip/hip_runtime.h>

// spec (32, 4000, 161, 2) f32.
//   pow[b,t,k]  = re^2 + im^2
//   g0[b,t]     = sqrt((2*sum(pow) - pow[0] - pow[160]) / 320)
//   gain[b,t]   = EMA over t: c = 0.9c + 0.1*g0  (gain[b,0]=g0[b,0])
//   new_spec    = spec / (gain + 0.001)
// Outputs flat-concat: new_spec (41,216,000 f32) then gain (128,000 f32).

typedef float f32x4 __attribute__((ext_vector_type(4)));
typedef float f32x2 __attribute__((ext_vector_type(2)));

#define B_SZ 32
#define T_SZ 4000
#define BINS 161
#define FRAME_F 322            // floats per frame
#define FRAMES (B_SZ * T_SZ)   // 128000
#define N_SPEC ((size_t)FRAMES * FRAME_F)  // 41,216,000
#define N4 (N_SPEC / 4)        // 10,304,000 (exact)
#define EMA_W 384              // 0.9^384 ~ 4e-18: below f32 resolution

// ---- K1: per-frame gain g0. One 64-lane wave per frame, float4 loads. ----
__global__ __launch_bounds__(256) void k_frame_gain(
    const float* __restrict__ spec, float* __restrict__ g0) {
  int gtid = blockIdx.x * 256 + threadIdx.x;
  int wid  = gtid >> 6;          // frame id
  int lane = threadIdx.x & 63;
  if (wid >= FRAMES) return;

  const float* fp = spec + (size_t)wid * FRAME_F;

  // round 0: f4 index = lane (bytes 0..1023, pairs 0..127)
  f32x4 v0 = *(const f32x4*)(fp + lane * 4);
  float s0 = v0.x * v0.x + v0.y * v0.y;
  float s1 = v0.z * v0.z + v0.w * v0.w;
  float acc = 2.0f * (s0 + s1);
  if (lane == 0) acc -= s0;                 // pow[0] has weight 1

  // round 1: lanes 0..15 f4 idx 64+lane (pairs 128..159); lane 16: pair 160
  if (lane < 16) {
    f32x4 v1 = *(const f32x4*)(fp + (64 + lane) * 4);
    acc += 2.0f * (v1.x * v1.x + v1.y * v1.y + v1.z * v1.z + v1.w * v1.w);
  } else if (lane == 16) {
    f32x2 v2 = *(const f32x2*)(fp + 320);
    acc += v2.x * v2.x + v2.y * v2.y;       // pow[160], weight 1
  }

#pragma unroll
  for (int off = 32; off > 0; off >>= 1) acc += __shfl_xor(acc, off, 64);
  if (lane == 0) g0[wid] = sqrtf(acc * (1.0f / 320.0f));
}

// ---- K2: EMA via truncated window (exact for t < EMA_W). ----
__global__ __launch_bounds__(256) void k_ema(
    const float* __restrict__ g0, float* __restrict__ gain_out) {
  __shared__ float xs[EMA_W + 256];
  int b  = blockIdx.y;
  int t0 = blockIdx.x * 256;
  int lo = t0 - (EMA_W - 1); if (lo < 0) lo = 0;
  int hi = t0 + 256; if (hi > T_SZ) hi = T_SZ;   // exclusive
  int n  = hi - lo;
  const float* gb = g0 + b * T_SZ;

  for (int i = threadIdx.x; i < n; i += 256) xs[i] = gb[lo + i];
  __syncthreads();

  int t = t0 + (int)threadIdx.x;
  if (t >= T_SZ) return;
  int s = t - (EMA_W - 1); if (s < 1) s = 1;
  float c = (s == 1) ? xs[0] : 0.f;   // lo==0 whenever s==1
  for (int k = s; k <= t; ++k) c = c * 0.9f + xs[k - lo] * 0.1f;
  gain_out[b * T_SZ + t] = c;
}

// ---- K3: flat float4 stream: out = spec / (gain + 0.001). ----
__global__ __launch_bounds__(256) void k_apply(
    const float* __restrict__ spec, const float* __restrict__ gain,
    float* __restrict__ out) {
  size_t i = (size_t)blockIdx.x * 256 + threadIdx.x;  // float4 index
  if (i >= N4) return;
  f32x4 v = ((const f32x4*)spec)[i];
  unsigned p0 = (unsigned)(2 * i);          // pair index of (v.x, v.y)
  unsigned f0 = p0 / 161u;                  // frame of pair p0 (magic mul)
  unsigned f1 = (p0 + 1) / 161u;            // frame of pair p0+1
  float inv0 = 1.0f / (gain[f0] + 0.001f);
  float inv1 = 1.0f / (gain[f1] + 0.001f);
  f32x4 r;
  r.x = v.x * inv0; r.y = v.y * inv0;
  r.z = v.z * inv1; r.w = v.w * inv1;
  // nontemporal: don't let the write stream evict spec from Infinity Cache
  __builtin_nontemporal_store(r, (f32x4*)out + i);
}

extern "C" void kernel_launch(void* const* d_in, const int* in_sizes, int n_in,
                              void* d_out, int out_size, void* d_ws, size_t ws_size,
                              hipStream_t stream) {
  const float* spec = (const float*)d_in[0];
  float* out  = (float*)d_out;
  float* gain = out + N_SPEC;        // gain output lives in the d_out tail
  float* g0   = (float*)d_ws;        // 128000 f32 scratch

  // K1: 4 frames (waves) per 256-thread block
  int blocks1 = (FRAMES + 3) / 4;
  k_frame_gain<<<blocks1, 256, 0, stream>>>(spec, g0);

  // K2: grid (T/256, B)
  dim3 g2((T_SZ + 255) / 256, B_SZ);
  k_ema<<<g2, 256, 0, stream>>>(g0, gain);

  // K3: flat float4 stream
  int blocks3 = (int)((N4 + 255) / 256);
  k_apply<<<blocks3, 256, 0, stream>>>(spec, gain, out);
}